// Round 3
// baseline (289.649 us; speedup 1.0000x reference)
//
#include <hip/hip_runtime.h>

// ---------------------------------------------------------------------------
// AttentionBlock: out = softmax((xWq^T)(xWk^T)^T / sqrt(512)) (xWv^T)
// R2: attn -> QBLK=64, 8 waves, dbuf K/V in LDS, raw s_barrier + counted
//     s_waitcnt (no vmcnt(0) drains), setprio around MFMA clusters.
// ---------------------------------------------------------------------------

typedef __bf16 bf16x8 __attribute__((ext_vector_type(8)));
typedef __bf16 bf16x4 __attribute__((ext_vector_type(4)));
typedef float  f32x4  __attribute__((ext_vector_type(4)));

constexpr int SEQ = 2048;
constexpr int DM  = 512;
constexpr int NB  = 8;
constexpr int GS  = NB * SEQ;    // 16384
constexpr int NT2 = SEQ / 32;    // 64 kv tiles of 32

__device__ __forceinline__ void gl16(const void* g, void* l) {
  __builtin_amdgcn_global_load_lds((const __attribute__((address_space(1))) void*)g,
                                   (__attribute__((address_space(3))) void*)l, 16, 0, 0);
}

__device__ __forceinline__ f32x4 mfma16(bf16x8 a, bf16x8 b, f32x4 c) {
  return __builtin_amdgcn_mfma_f32_16x16x32_bf16(a, b, c, 0, 0, 0);
}

// ---------------------------------------------------------------------------
// Kernel 0: fp32 -> bf16 conversion (x + 3 weights), float4 vectorized
// ---------------------------------------------------------------------------
__global__ void convert_kernel(const float* __restrict__ x,
                               const float* __restrict__ wq,
                               const float* __restrict__ wk,
                               const float* __restrict__ wv,
                               __bf16* __restrict__ xb,
                               __bf16* __restrict__ wqb,
                               __bf16* __restrict__ wkb,
                               __bf16* __restrict__ wvb) {
  const int NX4 = (GS * DM) / 4;
  const int NW4 = (DM * DM) / 4;
  const int stride = gridDim.x * blockDim.x;
  const int tid = blockIdx.x * blockDim.x + threadIdx.x;
  for (int i = tid; i < NX4; i += stride) {
    float4 v = ((const float4*)x)[i];
    bf16x4 o = { (__bf16)v.x, (__bf16)v.y, (__bf16)v.z, (__bf16)v.w };
    ((bf16x4*)xb)[i] = o;
  }
  for (int i = tid; i < NW4; i += stride) {
    float4 v = ((const float4*)wq)[i];
    bf16x4 o = { (__bf16)v.x, (__bf16)v.y, (__bf16)v.z, (__bf16)v.w };
    ((bf16x4*)wqb)[i] = o;
  }
  for (int i = tid; i < NW4; i += stride) {
    float4 v = ((const float4*)wk)[i];
    bf16x4 o = { (__bf16)v.x, (__bf16)v.y, (__bf16)v.z, (__bf16)v.w };
    ((bf16x4*)wkb)[i] = o;
  }
  for (int i = tid; i < NW4; i += stride) {
    float4 v = ((const float4*)wv)[i];
    bf16x4 o = { (__bf16)v.x, (__bf16)v.y, (__bf16)v.z, (__bf16)v.w };
    ((bf16x4*)wvb)[i] = o;
  }
}

// ---------------------------------------------------------------------------
// Kernel 1: NT GEMM  C[M][N] = A[M][512] * B[N][512]^T   (bf16 in, bf16 out)
// ---------------------------------------------------------------------------
__global__ __launch_bounds__(256, 2) void gemm_nt_kernel(
    const __bf16* __restrict__ A, const __bf16* __restrict__ Bm,
    __bf16* __restrict__ C, int N) {
  __shared__ __bf16 As[128 * 32];
  __shared__ __bf16 Bs[128 * 32];
  const int t = threadIdx.x;
  const int w = t >> 6, l = t & 63;
  const int l15 = l & 15, lg = l >> 4;
  const int m0 = blockIdx.x * 128, n0 = blockIdx.y * 128;
  const int wr = w >> 1, wc = w & 1;

  f32x4 acc[4][4] = {};
  const char* Ab = (const char*)A + (size_t)m0 * (DM * 2);
  const char* Bb = (const char*)Bm + (size_t)n0 * (DM * 2);

  for (int k0 = 0; k0 < DM; k0 += 32) {
#pragma unroll
    for (int i = 0; i < 2; ++i) {
      const int f = (i * 256 + t) * 16;
      const int row = f >> 6, c = f & 63;
      gl16(Ab + (size_t)row * (DM * 2) + k0 * 2 + c, (char*)As + f);
      gl16(Bb + (size_t)row * (DM * 2) + k0 * 2 + c, (char*)Bs + f);
    }
    __syncthreads();
    bf16x8 af[4], bfr[4];
#pragma unroll
    for (int mi = 0; mi < 4; ++mi)
      af[mi] = *(const bf16x8*)((const char*)As + (wr * 64 + mi * 16 + l15) * 64 + lg * 16);
#pragma unroll
    for (int ni = 0; ni < 4; ++ni)
      bfr[ni] = *(const bf16x8*)((const char*)Bs + (wc * 64 + ni * 16 + l15) * 64 + lg * 16);
#pragma unroll
    for (int mi = 0; mi < 4; ++mi)
#pragma unroll
      for (int ni = 0; ni < 4; ++ni)
        acc[mi][ni] = mfma16(af[mi], bfr[ni], acc[mi][ni]);
    __syncthreads();
  }
#pragma unroll
  for (int mi = 0; mi < 4; ++mi)
#pragma unroll
    for (int ni = 0; ni < 4; ++ni)
#pragma unroll
      for (int r = 0; r < 4; ++r) {
        const int row = m0 + wr * 64 + mi * 16 + lg * 4 + r;
        const int col = n0 + wc * 64 + ni * 16 + l15;
        C[(size_t)row * N + col] = (__bf16)acc[mi][ni][r];
      }
}

// ---------------------------------------------------------------------------
// Kernel 2: fused flash attention (R2 schedule).
// Grid: 256 blocks; b = bid&7 (XCD-matched), q0 = (bid>>3)*64. 512 thr/8 waves.
// QK^T: wave w -> rows (w>>1)*16, cols (w&1)*16 of S[64][32]; Q in regs.
// PV:   wave w -> e-cols [w*64, w*64+64), all 64 q rows (o[4][4]).
// LDS: dbuf Ks[2][32][512] + Vs[2][512][32] (XOR-swizzled) = 128KB,
//      Ss 9.2KB, Ps 4KB, stats -> ~145KB, 1 block/CU.
// Sync: raw s_barrier + asm waitcnt; prefetch K/V[it+1] issued right after
//       top barrier -> full iteration to land; top drain nominally free.
// ---------------------------------------------------------------------------
__global__ __launch_bounds__(512, 2) void attn_kernel(
    const __bf16* __restrict__ QK, const __bf16* __restrict__ Vt,
    float* __restrict__ Out) {
  __shared__ __bf16 Ks[2][32 * 512];
  __shared__ __bf16 Vs[2][512 * 32];
  __shared__ float  Ss[64 * 36];
  __shared__ __bf16 Ps[64 * 32];
  __shared__ float  m_s[64], l_s[64], corr_s[64];
  __shared__ int    flags_s[8];

  const int t = threadIdx.x;
  const int w = t >> 6, l = t & 63;
  const int l15 = l & 15, lg = l >> 4;
  const int b = blockIdx.x & 7;
  const int q0 = (blockIdx.x >> 3) * 64;
  const int qi = w >> 1, kj = w & 1;

  // per-thread staging offsets (swizzle pre-applied on global source)
  int ksrc[4], vsrc[4], ldst[4];
#pragma unroll
  for (int i = 0; i < 4; ++i) {
    const int f = (i * 512 + t) * 16;
    ldst[i] = f;
    const int krow = f >> 10, kc = f & 1023;
    ksrc[i] = krow * 2048 + (kc ^ ((krow & 7) << 4));
    const int e = f >> 6, c2 = f & 63;
    vsrc[i] = e * (GS * 2) + (c2 ^ ((e & 3) << 4));
  }

  const char* Kb = (const char*)QK + (size_t)b * SEQ * 2048 + 1024;  // K cols
  const char* Vb = (const char*)Vt + (size_t)b * SEQ * 2;

  // Q fragments: rows q0 + qi*16 + l15, full D=512 (64 VGPR)
  bf16x8 qf[16];
  {
    const char* Qb = (const char*)QK +
        (size_t)(b * SEQ + q0 + qi * 16 + l15) * 2048 + lg * 16;
#pragma unroll
    for (int ks = 0; ks < 16; ++ks)
      qf[ks] = *(const bf16x8*)(Qb + ks * 64);
  }

  f32x4 o[4][4] = {};
  if (t < 64) { m_s[t] = -__builtin_inff(); l_s[t] = 0.f; }

  // prologue: stage tile 0 into buf 0
#pragma unroll
  for (int i = 0; i < 4; ++i) gl16(Kb + ksrc[i], (char*)&Ks[0][0] + ldst[i]);
#pragma unroll
  for (int i = 0; i < 4; ++i) gl16(Vb + vsrc[i], (char*)&Vs[0][0] + ldst[i]);

  const float SCL = 0.0637639022f;  // log2(e)/sqrt(512)

  for (int it = 0; it < NT2; ++it) {
    const int cur = it & 1;

    // top: K/V[it] (issued >=1 full iteration ago) must be landed; publish.
    asm volatile("s_waitcnt vmcnt(0) lgkmcnt(0)" ::: "memory");
    __builtin_amdgcn_s_barrier();

    // prefetch K/V[it+1] into buf[cur^1] (licensed by the barrier above)
    {
      const int kvn = (it + 1 < NT2 ? it + 1 : 0) * 32;
      char* kdst = (char*)&Ks[cur ^ 1][0];
      char* vdst = (char*)&Vs[cur ^ 1][0];
#pragma unroll
      for (int i = 0; i < 4; ++i) gl16(Kb + (size_t)kvn * 2048 + ksrc[i], kdst + ldst[i]);
#pragma unroll
      for (int i = 0; i < 4; ++i) gl16(Vb + (size_t)kvn * 2 + vsrc[i], vdst + ldst[i]);
    }

    // ---- QK^T on Ks[cur] (two 8-deep MFMA chains) ----
    {
      f32x4 s0 = {}, s1 = {};
      const int krow = kj * 16 + l15;
      const char* KsR = (const char*)&Ks[cur][0] + krow * 1024;
      const int ksw = (krow & 7) << 4;
      __builtin_amdgcn_s_setprio(1);
#pragma unroll
      for (int ks = 0; ks < 8; ++ks) {
        bf16x8 kf0 = *(const bf16x8*)(KsR + ((ks * 64 + lg * 16) ^ ksw));
        bf16x8 kf1 = *(const bf16x8*)(KsR + (((ks + 8) * 64 + lg * 16) ^ ksw));
        s0 = mfma16(qf[ks], kf0, s0);
        s1 = mfma16(qf[ks + 8], kf1, s1);
      }
      __builtin_amdgcn_s_setprio(0);
      s0 = s0 + s1;
#pragma unroll
      for (int r = 0; r < 4; ++r)
        Ss[(qi * 16 + lg * 4 + r) * 36 + kj * 16 + l15] = s0[r] * SCL;
    }
    asm volatile("s_waitcnt lgkmcnt(0)" ::: "memory");
    __builtin_amdgcn_s_barrier();

    // ---- online softmax: 8 threads per row, 4 scores each ----
    {
      const int row = t >> 3, c8 = t & 7;
      float4 v0 = *(const float4*)&Ss[row * 36 + c8 * 4];
      float tmax = fmaxf(fmaxf(v0.x, v0.y), fmaxf(v0.z, v0.w));
      tmax = fmaxf(tmax, __shfl_xor(tmax, 1));
      tmax = fmaxf(tmax, __shfl_xor(tmax, 2));
      tmax = fmaxf(tmax, __shfl_xor(tmax, 4));
      const float mold = m_s[row];
      const float mnew = fmaxf(mold, tmax);
      const float corr = exp2f(mold - mnew);   // exactly 1.0f when no new max
      const float p0 = exp2f(v0.x - mnew), p1 = exp2f(v0.y - mnew);
      const float p2 = exp2f(v0.z - mnew), p3 = exp2f(v0.w - mnew);
      float rsum = (p0 + p1) + (p2 + p3);
      rsum += __shfl_xor(rsum, 1);
      rsum += __shfl_xor(rsum, 2);
      rsum += __shfl_xor(rsum, 4);
      if (c8 == 0) { m_s[row] = mnew; l_s[row] = l_s[row] * corr + rsum; corr_s[row] = corr; }
      const int allskip = __all(corr == 1.0f);
      if (l == 0) flags_s[w] = allskip;
      bf16x4 pb = { (__bf16)p0, (__bf16)p1, (__bf16)p2, (__bf16)p3 };
      *(bf16x4*)((char*)Ps + row * 64 + (((c8 >> 1) * 16) ^ ((row & 3) << 4)) +
                 (c8 & 1) * 8) = pb;
    }
    asm volatile("s_waitcnt lgkmcnt(0)" ::: "memory");
    __builtin_amdgcn_s_barrier();

    // ---- PV on Vs[cur] ----
    {
      int fl = 1;
#pragma unroll
      for (int i = 0; i < 8; ++i) fl &= flags_s[i];
      if (!fl) {
#pragma unroll
        for (int mi = 0; mi < 4; ++mi) {
          float cr[4];
#pragma unroll
          for (int r = 0; r < 4; ++r) cr[r] = corr_s[mi * 16 + lg * 4 + r];
#pragma unroll
          for (int ni = 0; ni < 4; ++ni)
#pragma unroll
            for (int r = 0; r < 4; ++r) o[mi][ni][r] *= cr[r];
        }
      }
      bf16x8 pf[4];
#pragma unroll
      for (int mi = 0; mi < 4; ++mi) {
        const int prow = mi * 16 + l15;
        pf[mi] = *(const bf16x8*)((const char*)Ps + prow * 64 +
                                  ((lg * 16) ^ ((prow & 3) << 4)));
      }
      __builtin_amdgcn_s_setprio(1);
#pragma unroll
      for (int ni = 0; ni < 4; ++ni) {
        const int er = w * 64 + ni * 16 + l15;
        bf16x8 vf = *(const bf16x8*)((const char*)&Vs[cur][0] + er * 64 +
                                     ((lg * 16) ^ ((er & 3) << 4)));
#pragma unroll
        for (int mi = 0; mi < 4; ++mi)
          o[mi][ni] = mfma16(pf[mi], vf, o[mi][ni]);
      }
      __builtin_amdgcn_s_setprio(0);
    }
  }

  // ---- epilogue: normalize, write fp32 ----
#pragma unroll
  for (int mi = 0; mi < 4; ++mi) {
    float rl[4];
#pragma unroll
    for (int r = 0; r < 4; ++r) rl[r] = 1.0f / l_s[mi * 16 + lg * 4 + r];
#pragma unroll
    for (int ni = 0; ni < 4; ++ni)
#pragma unroll
      for (int r = 0; r < 4; ++r) {
        const int row = q0 + mi * 16 + lg * 4 + r;
        const int col = w * 64 + ni * 16 + l15;
        Out[((size_t)b * SEQ + row) * DM + col] = o[mi][ni][r] * rl[r];
      }
  }
}

// ---------------------------------------------------------------------------
// Launcher. Workspace (bytes, total 68,681,728):
//   xb 0 | wqkb 16777216 (Wq;Wk) | wvb 17825792 | qk 18350080
//   ([16384][1024]: Q cols 0..511, K cols 512..1023) | vt 51904512
// ---------------------------------------------------------------------------
extern "C" void kernel_launch(void* const* d_in, const int* in_sizes, int n_in,
                              void* d_out, int out_size, void* d_ws, size_t ws_size,
                              hipStream_t stream) {
  const float* x  = (const float*)d_in[0];
  const float* wq = (const float*)d_in[1];
  const float* wk = (const float*)d_in[2];
  const float* wv = (const float*)d_in[3];
  float* out = (float*)d_out;
  char* ws = (char*)d_ws;

  __bf16* xb   = (__bf16*)(ws);
  __bf16* wqkb = (__bf16*)(ws + 16777216);
  __bf16* wvb  = (__bf16*)(ws + 17825792);
  __bf16* qk   = (__bf16*)(ws + 18350080);
  __bf16* vt   = (__bf16*)(ws + 51904512);

  convert_kernel<<<2048, 256, 0, stream>>>(x, wq, wk, wv,
                                           xb, wqkb, wqkb + 262144, wvb);
  // [Q|K] = x * [Wq;Wk]^T : [16384x1024]
  gemm_nt_kernel<<<dim3(GS / 128, 1024 / 128), 256, 0, stream>>>(xb, wqkb, qk, 1024);
  // Vt[e][gs] = Wv * x^T : [512x16384]
  gemm_nt_kernel<<<dim3(DM / 128, GS / 128), 256, 0, stream>>>(wvb, xb, vt, GS);
  // fused attention
  attn_kernel<<<256, 512, 0, stream>>>(qk, vt, out);
}